// Round 12
// baseline (1406.637 us; speedup 1.0000x reference)
//
#include <hip/hip_runtime.h>
#include <hip/hip_cooperative_groups.h>

namespace cg = cooperative_groups;

#define D 64
#define BN_EPS 1e-5f
#define NPART 8

// ---------------------------------------------------------------------------
// helpers
// ---------------------------------------------------------------------------
__device__ __forceinline__ ushort f2bf(float x) {
    uint u = __float_as_uint(x);
    u += 0x7fffu + ((u >> 16) & 1u); // RNE
    return (ushort)(u >> 16);
}
__device__ __forceinline__ float bflo(uint u) { return __uint_as_float(u << 16); }
__device__ __forceinline__ float bfhi(uint u) { return __uint_as_float(u & 0xffff0000u); }

// ---------------------------------------------------------------------------
// CSR build — hist/fill partitioned by dst range so each partition's scattered
// writes/atomics stay in one XCD's L2 (blockIdx%8 == XCD round-robin) and merge
// before writeback.
// ---------------------------------------------------------------------------
__global__ __launch_bounds__(256) void hist_kernel(const int* __restrict__ edst, int E, int N,
                                                   int* __restrict__ counts, uint* __restrict__ hwBase) {
    // zero the two dummy gather half-rows (row N of each half, 64 B each)
    if (blockIdx.x == gridDim.x - 1 && threadIdx.x < 32) {
        int t = threadIdx.x;
        size_t idx = (t < 16) ? ((size_t)N * 16 + t)
                              : ((size_t)(2 * N + 1) * 16 + (t - 16));
        hwBase[idx] = 0u;
    }
    int part = blockIdx.x & (NPART - 1);
    int bIdx = blockIdx.x / NPART;
    int nblk = gridDim.x / NPART;
    int partN = (N + NPART - 1) / NPART;
    int nlo = part * partN;
    int nhi = min(N, nlo + partN);
    int E4 = E >> 2;
    const int4* d4 = (const int4*)edst;
    for (int i = bIdx * 256 + threadIdx.x; i < E4; i += nblk * 256) {
        int4 d = d4[i];
        if (d.x >= nlo && d.x < nhi) atomicAdd(&counts[d.x], 1);
        if (d.y >= nlo && d.y < nhi) atomicAdd(&counts[d.y], 1);
        if (d.z >= nlo && d.z < nhi) atomicAdd(&counts[d.z], 1);
        if (d.w >= nlo && d.w < nhi) atomicAdd(&counts[d.w], 1);
    }
    if (blockIdx.x == 0) {
        for (int e = (E4 << 2) + threadIdx.x; e < E; e += 256) atomicAdd(&counts[edst[e]], 1);
    }
}

__global__ void scan1_kernel(const int* __restrict__ counts, int N,
                             int* __restrict__ rowptr, int* __restrict__ bsums,
                             float* __restrict__ dinv) {
    __shared__ int s[256];
    int i = blockIdx.x * 256 + threadIdx.x;
    int v = (i < N) ? counts[i] : 0;
    s[threadIdx.x] = v;
    __syncthreads();
    for (int off = 1; off < 256; off <<= 1) {
        int t = (threadIdx.x >= off) ? s[threadIdx.x - off] : 0;
        __syncthreads();
        s[threadIdx.x] += t;
        __syncthreads();
    }
    if (i < N) {
        rowptr[i + 1] = s[threadIdx.x];
        dinv[i] = rsqrtf((float)(v + 1));
    }
    if (threadIdx.x == 255) bsums[blockIdx.x] = s[255];
}

__global__ void scan2_kernel(const int* __restrict__ bsums, int nb, int* __restrict__ boff) {
    __shared__ int s[512];
    int v = (threadIdx.x < nb) ? bsums[threadIdx.x] : 0;
    s[threadIdx.x] = v;
    __syncthreads();
    for (int off = 1; off < 512; off <<= 1) {
        int t = (threadIdx.x >= off) ? s[threadIdx.x - off] : 0;
        __syncthreads();
        s[threadIdx.x] += t;
        __syncthreads();
    }
    if (threadIdx.x < nb) boff[threadIdx.x] = s[threadIdx.x] - v; // exclusive
}

__global__ void scan3_kernel(int* __restrict__ rowptr, const int* __restrict__ boff, int N,
                             int* __restrict__ cursor) {
    int i = blockIdx.x * 256 + threadIdx.x;
    if (i == 0) { rowptr[0] = 0; cursor[0] = 0; }
    if (i < N) {
        int v = rowptr[i + 1] + boff[i >> 8];
        rowptr[i + 1] = v;
        if (i + 1 < N) cursor[i + 1] = v;
    }
}

__global__ __launch_bounds__(256) void fill_kernel(const int* __restrict__ esrc,
                                                   const int* __restrict__ edst, int E, int N,
                                                   int* __restrict__ cursor, int* __restrict__ col) {
    int part = blockIdx.x & (NPART - 1);
    int bIdx = blockIdx.x / NPART;
    int nblk = gridDim.x / NPART;
    int partN = (N + NPART - 1) / NPART;
    int nlo = part * partN;
    int nhi = min(N, nlo + partN);
    int E4 = E >> 2;
    const int4* d4 = (const int4*)edst;
    const int4* s4 = (const int4*)esrc;
    for (int i = bIdx * 256 + threadIdx.x; i < E4; i += nblk * 256) {
        int4 d = d4[i];
        bool mx = (d.x >= nlo) & (d.x < nhi);
        bool my = (d.y >= nlo) & (d.y < nhi);
        bool mz = (d.z >= nlo) & (d.z < nhi);
        bool mw = (d.w >= nlo) & (d.w < nhi);
        if (mx | my | mz | mw) {
            int4 s = s4[i];
            if (mx) col[atomicAdd(&cursor[d.x], 1)] = s.x;
            if (my) col[atomicAdd(&cursor[d.y], 1)] = s.y;
            if (mz) col[atomicAdd(&cursor[d.z], 1)] = s.z;
            if (mw) col[atomicAdd(&cursor[d.w], 1)] = s.w;
        }
    }
    if (blockIdx.x == 0) {
        for (int e = (E4 << 2) + threadIdx.x; e < E; e += 256) {
            int d = edst[e];
            col[atomicAdd(&cursor[d], 1)] = esrc[e];
        }
    }
}

// ---------------------------------------------------------------------------
// Cooperative mega-kernel: for each layer, {GEMM -> grid.sync -> AGG -> grid.sync},
// then final BN+ReLU. Replaces 9 dispatches with 1.
//   hW : half-split bf16 [2][(N+1)][32]  (dinv-scaled h@W; row N = zero dummy)
//   B  : half-split bf16 [2][N][32]      (pre-norm h)
//   stats[l*128 + {0|64} + f] : per-layer BN sum/sumsq (zeroed by host memset)
// LDS budget ~25 KB -> 6 blocks/CU -> agg phase can hold 24 waves/CU (75%).
// ---------------------------------------------------------------------------
__global__ __launch_bounds__(256, 6) void mega_kernel(
    const float* __restrict__ x,
    const float* __restrict__ Ws,
    const float* __restrict__ gammas,
    const float* __restrict__ betas,
    const float* __restrict__ dinv,
    const int* __restrict__ rowptr,
    const int* __restrict__ col,
    ushort* __restrict__ hW,
    ushort* __restrict__ B,
    float* __restrict__ stats,
    float* __restrict__ out,
    int N)
{
    cg::grid_group grid = cg::this_grid();
    __shared__ char smem[16384 + 8192 + 512];
    float (*in_t)[64] = (float (*)[64])smem;          // gemm: [k][row] f32, 16 KB
    ushort* Wl        = (ushort*)(smem + 16384);      // gemm: [k][col] bf16, 8 KB
    float* bnl        = (float*)(smem + 16384 + 8192);// scale[64], shift[64]
    float* red        = (float*)smem;                 // agg: [4][64] partials (reuses in_t)

    const int t = threadIdx.x;
    const int G = gridDim.x;      // multiple of 8
    const int T = (N + 63) >> 6;  // gemm 64-row tiles

    for (int l = 0; l < 4; ++l) {
        // ---------------- GEMM phase ----------------
        {
            const float* W = Ws + l * 4096;
            if (l > 0 && t < 64) {
                const float* st = stats + (size_t)(l - 1) * 128;
                float invN = 1.f / (float)N;
                float mean = st[t] * invN;
                float var  = st[64 + t] * invN - mean * mean;
                float sc   = gammas[(l - 1) * 64 + t] * rsqrtf(var + BN_EPS);
                bnl[t]      = sc;
                bnl[64 + t] = betas[(l - 1) * 64 + t] - mean * sc;
            }
            // stage W as bf16 (rounding: ~0.4% rel, within error budget)
            for (int i = t; i < 2048; i += 256) {
                float2 w2 = ((const float2*)W)[i];
                ((uint*)Wl)[i] = ((uint)f2bf(w2.y) << 16) | (uint)f2bf(w2.x);
            }
            int wv = t >> 6, r = t & 63;
            int rg = t & 15, cgi = t >> 4;
            for (int tile = blockIdx.x; tile < T; tile += G) {
                int n0 = tile << 6;
                int row = n0 + r;
                __syncthreads(); // bnl/Wl visible; previous tile's reads done
                if (l == 0) {
                    int fb = wv * 16;
                    if (row < N) {
                        const float4* src = (const float4*)(x + (size_t)row * 64 + fb);
#pragma unroll
                        for (int j2 = 0; j2 < 4; ++j2) {
                            float4 v = src[j2];
                            int f = fb + 4 * j2;
                            in_t[f][r] = v.x; in_t[f + 1][r] = v.y;
                            in_t[f + 2][r] = v.z; in_t[f + 3][r] = v.w;
                        }
                    } else {
#pragma unroll
                        for (int j2 = 0; j2 < 16; ++j2) in_t[fb + j2][r] = 0.f;
                    }
                } else {
                    int hh = wv >> 1, sub = wv & 1;
                    int fb = 32 * hh + 16 * sub;
                    if (row < N) {
                        const uint* src = (const uint*)(B + ((size_t)hh * N + row) * 32 + sub * 16);
#pragma unroll
                        for (int j2 = 0; j2 < 8; ++j2) {
                            uint u = src[j2];
                            int f = fb + 2 * j2;
                            in_t[f][r]     = fmaxf(fmaf(bflo(u), bnl[f],     bnl[64 + f]),     0.f);
                            in_t[f + 1][r] = fmaxf(fmaf(bfhi(u), bnl[f + 1], bnl[64 + f + 1]), 0.f);
                        }
                    } else {
#pragma unroll
                        for (int j2 = 0; j2 < 16; ++j2) in_t[fb + j2][r] = 0.f;
                    }
                }
                __syncthreads();
                float acc[4][4];
#pragma unroll
                for (int i = 0; i < 4; ++i)
#pragma unroll
                    for (int j2 = 0; j2 < 4; ++j2) acc[i][j2] = 0.f;
#pragma unroll 8
                for (int k = 0; k < 64; ++k) {
                    float4 a = *(const float4*)&in_t[k][4 * rg];
                    ushort4 bw = *(const ushort4*)&Wl[k * 64 + 4 * cgi];
                    float br[4] = {__uint_as_float((uint)bw.x << 16),
                                   __uint_as_float((uint)bw.y << 16),
                                   __uint_as_float((uint)bw.z << 16),
                                   __uint_as_float((uint)bw.w << 16)};
                    float ar[4] = {a.x, a.y, a.z, a.w};
#pragma unroll
                    for (int i = 0; i < 4; ++i)
#pragma unroll
                        for (int j2 = 0; j2 < 4; ++j2)
                            acc[i][j2] = fmaf(ar[i], br[j2], acc[i][j2]);
                }
                int oh = cgi >> 3; // output feature half
                uint2* dst = (uint2*)(hW + (size_t)oh * (N + 1) * 32);
#pragma unroll
                for (int i = 0; i < 4; ++i) {
                    int row2 = n0 + 4 * rg + i;
                    if (row2 < N) {
                        float dn = dinv[row2];
                        uint2 pk;
                        pk.x = ((uint)f2bf(acc[i][1] * dn) << 16) | (uint)f2bf(acc[i][0] * dn);
                        pk.y = ((uint)f2bf(acc[i][3] * dn) << 16) | (uint)f2bf(acc[i][2] * dn);
                        dst[(size_t)row2 * 8 + (cgi & 7)] = pk;
                    }
                }
            }
        }
        grid.sync();
        // ---------------- AGG phase (R8 structure) ----------------
        {
            int part = blockIdx.x & 7;
            int h    = part >> 2;                            // feature half (XCD quads)
            int bIdxH = (blockIdx.x >> 3) * 4 + (part & 3);  // block idx within half
            const uint2* hw2 = (const uint2*)(hW + (size_t)h * (N + 1) * 32);
            uint2* out2 = (uint2*)(B + (size_t)h * N * 32);
            int lane = t & 63;
            int wv   = t >> 6;
            int g    = lane >> 3;    // group 0..7 (edge slot)
            int j    = lane & 7;     // feature quad within half
            float s4[4] = {0.f,0.f,0.f,0.f}, q4[4] = {0.f,0.f,0.f,0.f};
            int gw = bIdxH * 4 + wv;
            int nw = (G >> 1) * 4;   // waves per half
            for (int n = gw; n < N; n += nw) {
                int e0 = rowptr[n], e1 = rowptr[n + 1];
                float a[4] = {0.f,0.f,0.f,0.f};
                if (g == 0) {
                    uint2 us = hw2[(size_t)n * 8 + j];
                    a[0] = bflo(us.x); a[1] = bfhi(us.x); a[2] = bflo(us.y); a[3] = bfhi(us.y);
                }
                int m = e1 - 1;
                for (int eb = e0; eb < e1; eb += 32) {
                    int cc[4]; uint2 uu[4];
#pragma unroll
                    for (int u = 0; u < 4; ++u) {
                        int e = eb + 8 * u + g;
                        bool ok = e < e1;
                        int c = col[ok ? e : m];
                        cc[u] = ok ? c : N; // dummy zero row when past end
                    }
#pragma unroll
                    for (int u = 0; u < 4; ++u) uu[u] = hw2[(size_t)cc[u] * 8 + j];
#pragma unroll
                    for (int u = 0; u < 4; ++u) {
                        a[0] += bflo(uu[u].x); a[1] += bfhi(uu[u].x);
                        a[2] += bflo(uu[u].y); a[3] += bfhi(uu[u].y);
                    }
                }
#pragma unroll
                for (int k = 0; k < 4; ++k) {
                    a[k] += __shfl(a[k], lane ^ 8);
                    a[k] += __shfl(a[k], lane ^ 16);
                    a[k] += __shfl(a[k], lane ^ 32);
                }
                if (g == 0) {
                    float dn = dinv[n];
#pragma unroll
                    for (int k = 0; k < 4; ++k) { a[k] *= dn; s4[k] += a[k]; q4[k] += a[k] * a[k]; }
                    uint2 pk;
                    pk.x = ((uint)f2bf(a[1]) << 16) | (uint)f2bf(a[0]);
                    pk.y = ((uint)f2bf(a[3]) << 16) | (uint)f2bf(a[2]);
                    out2[(size_t)n * 8 + j] = pk;
                }
            }
            // block-level BN stats for this half's 32 features
            if (g == 0) {
#pragma unroll
                for (int k = 0; k < 4; ++k) {
                    red[wv * 64 + 4 * j + k]      = s4[k];
                    red[wv * 64 + 32 + 4 * j + k] = q4[k];
                }
            }
            __syncthreads();
            if (t < 64) {
                float v = red[t] + red[64 + t] + red[128 + t] + red[192 + t];
                int f = t & 31;
                int base = (t < 32) ? 0 : 64; // sum vs sumsq
                atomicAdd(&stats[(size_t)l * 128 + base + 32 * h + f], v);
            }
        }
        grid.sync();
    }

    // ---------------- final BN + ReLU ----------------
    {
        if (t < 64) {
            const float* st = stats + 3 * 128;
            float invN = 1.f / (float)N;
            float mean = st[t] * invN;
            float var  = st[64 + t] * invN - mean * mean;
            float sc   = gammas[3 * 64 + t] * rsqrtf(var + BN_EPS);
            bnl[t]      = sc;
            bnl[64 + t] = betas[3 * 64 + t] - mean * sc;
        }
        __syncthreads();
        const uint* B32 = (const uint*)B;
        float2* o2 = (float2*)out;
        int total = N * 32;
        for (int i = blockIdx.x * 256 + t; i < total; i += G * 256) {
            int h = (i >= N * 16) ? 1 : 0;
            int rem = i - h * N * 16;
            int n = rem >> 4;
            int ju = rem & 15;
            int f2 = 32 * h + 2 * ju;
            uint u = B32[i];
            float a = fmaxf(fmaf(bflo(u), bnl[f2],     bnl[64 + f2]),     0.f);
            float b = fmaxf(fmaf(bfhi(u), bnl[f2 + 1], bnl[64 + f2 + 1]), 0.f);
            o2[(size_t)n * 32 + 16 * h + ju] = make_float2(a, b);
        }
    }
}

// ---------------------------------------------------------------------------
extern "C" void kernel_launch(void* const* d_in, const int* in_sizes, int n_in,
                              void* d_out, int out_size, void* d_ws, size_t ws_size,
                              hipStream_t stream) {
    const float* x      = (const float*)d_in[0];
    const int*   ei     = (const int*)d_in[1];
    const float* Ws     = (const float*)d_in[2];
    // d_in[3] = bs: cancels exactly under training-mode BatchNorm
    const float* gammas = (const float*)d_in[4];
    const float* betas  = (const float*)d_in[5];

    const int N = in_sizes[0] / D;           // 100000
    const int E = in_sizes[1] / 2;           // 1250000

    const int* esrc = ei;
    const int* edst = ei + E;

    char* w = (char*)d_ws;
    size_t off = 0;
    auto alloc = [&](size_t bytes) {
        void* p = w + off;
        off = (off + bytes + 255) & ~(size_t)255;
        return p;
    };
    ushort* hW     = (ushort*)alloc((size_t)2 * (N + 1) * 32 * sizeof(ushort)); // half-split bf16 (+dummy rows)
    ushort* B      = (ushort*)alloc((size_t)2 * N * 32 * sizeof(ushort));       // half-split bf16 pre-norm h
    int*    counts = (int*)alloc((size_t)N * sizeof(int));                      // | contiguous with
    float*  stats  = (float*)alloc(4 * 128 * sizeof(float));                    // | per-layer stats
    int*    rowptr = (int*)alloc((size_t)(N + 1) * sizeof(int));
    int*    cursor = (int*)alloc((size_t)(N + 1) * sizeof(int));
    float*  dinv   = (float*)alloc((size_t)N * sizeof(float));
    int*    col    = (int*)alloc((size_t)E * sizeof(int));
    int*    bsums  = (int*)alloc(512 * sizeof(int));
    int*    boff   = (int*)alloc(512 * sizeof(int));

    const int nbScan = (N + 255) / 256; // 391

    // single memset covers counts + (alignment pad) + stats
    (void)hipMemsetAsync(counts, 0, (size_t)((char*)(stats + 4 * 128) - (char*)counts), stream);

    // ---- degree + CSR ----
    hist_kernel<<<1024, 256, 0, stream>>>(edst, E, N, counts, (uint*)hW);
    scan1_kernel<<<nbScan, 256, 0, stream>>>(counts, N, rowptr, bsums, dinv);
    scan2_kernel<<<1, 512, 0, stream>>>(bsums, nbScan, boff);
    scan3_kernel<<<nbScan, 256, 0, stream>>>(rowptr, boff, N, cursor);
    fill_kernel<<<1024, 256, 0, stream>>>(esrc, edst, E, N, cursor, col);

    // ---- fused layers: one cooperative kernel ----
    int nbPerCU = 0;
    (void)hipOccupancyMaxActiveBlocksPerMultiprocessor(&nbPerCU, mega_kernel, 256, 0);
    if (nbPerCU < 1) nbPerCU = 1;
    int cus = 0;
    int devId = 0;
    (void)hipGetDevice(&devId);
    (void)hipDeviceGetAttribute(&cus, hipDeviceAttributeMultiprocessorCount, devId);
    if (cus <= 0) cus = 256;
    long Gl = (long)nbPerCU * (long)cus;
    if (Gl > 4096) Gl = 4096;
    int G = (int)(Gl & ~7L); // multiple of 8 for XCD-half partition
    if (G < 8) G = 8;

    int Nv = N;
    float* outF = (float*)d_out;
    void* kargs[] = {(void*)&x, (void*)&Ws, (void*)&gammas, (void*)&betas,
                     (void*)&dinv, (void*)&rowptr, (void*)&col,
                     (void*)&hW, (void*)&B, (void*)&stats, (void*)&outF, (void*)&Nv};
    (void)hipLaunchCooperativeKernel((void*)mega_kernel, dim3(G), dim3(256), kargs, 0, stream);
}

// Round 13
// 587.864 us; speedup vs baseline: 2.3928x; 2.3928x over previous
//
#include <hip/hip_runtime.h>

#define D 64
#define BN_EPS 1e-5f
#define NPART 8

// ---------------------------------------------------------------------------
// CSR build — hist/fill partitioned by dst range so each partition's scattered
// writes/atomics stay in one XCD's L2 (blockIdx%8 == XCD round-robin) and merge
// before writeback.
// ---------------------------------------------------------------------------
__global__ __launch_bounds__(256) void hist_kernel(const int* __restrict__ edst, int E, int N,
                                                   int* __restrict__ counts, uint* __restrict__ hwBase) {
    // zero the two dummy gather half-rows (row N of each half, 64 B each)
    if (blockIdx.x == gridDim.x - 1 && threadIdx.x < 32) {
        int t = threadIdx.x;
        size_t idx = (t < 16) ? ((size_t)N * 16 + t)
                              : ((size_t)(2 * N + 1) * 16 + (t - 16));
        hwBase[idx] = 0u;
    }
    int part = blockIdx.x & (NPART - 1);
    int bIdx = blockIdx.x / NPART;
    int nblk = gridDim.x / NPART;
    int partN = (N + NPART - 1) / NPART;
    int nlo = part * partN;
    int nhi = min(N, nlo + partN);
    int E4 = E >> 2;
    const int4* d4 = (const int4*)edst;
    for (int i = bIdx * 256 + threadIdx.x; i < E4; i += nblk * 256) {
        int4 d = d4[i];
        if (d.x >= nlo && d.x < nhi) atomicAdd(&counts[d.x], 1);
        if (d.y >= nlo && d.y < nhi) atomicAdd(&counts[d.y], 1);
        if (d.z >= nlo && d.z < nhi) atomicAdd(&counts[d.z], 1);
        if (d.w >= nlo && d.w < nhi) atomicAdd(&counts[d.w], 1);
    }
    if (blockIdx.x == 0) {
        for (int e = (E4 << 2) + threadIdx.x; e < E; e += 256) atomicAdd(&counts[edst[e]], 1);
    }
}

// inclusive block scan of counts; rowptr[i+1] = incl(i) (pre-offset); bsums[b] = block total
// also emits dinv[i] = rsqrt(count+1)  (self loop included)
__global__ void scan1_kernel(const int* __restrict__ counts, int N,
                             int* __restrict__ rowptr, int* __restrict__ bsums,
                             float* __restrict__ dinv) {
    __shared__ int s[256];
    int i = blockIdx.x * 256 + threadIdx.x;
    int v = (i < N) ? counts[i] : 0;
    s[threadIdx.x] = v;
    __syncthreads();
    for (int off = 1; off < 256; off <<= 1) {
        int t = (threadIdx.x >= off) ? s[threadIdx.x - off] : 0;
        __syncthreads();
        s[threadIdx.x] += t;
        __syncthreads();
    }
    if (i < N) {
        rowptr[i + 1] = s[threadIdx.x];
        dinv[i] = rsqrtf((float)(v + 1));
    }
    if (threadIdx.x == 255) bsums[blockIdx.x] = s[255];
}

__global__ void scan2_kernel(const int* __restrict__ bsums, int nb, int* __restrict__ boff) {
    __shared__ int s[512];
    int v = (threadIdx.x < nb) ? bsums[threadIdx.x] : 0;
    s[threadIdx.x] = v;
    __syncthreads();
    for (int off = 1; off < 512; off <<= 1) {
        int t = (threadIdx.x >= off) ? s[threadIdx.x - off] : 0;
        __syncthreads();
        s[threadIdx.x] += t;
        __syncthreads();
    }
    if (threadIdx.x < nb) boff[threadIdx.x] = s[threadIdx.x] - v; // exclusive
}

// apply block offsets; also seed cursor = final rowptr
__global__ void scan3_kernel(int* __restrict__ rowptr, const int* __restrict__ boff, int N,
                             int* __restrict__ cursor) {
    int i = blockIdx.x * 256 + threadIdx.x;
    if (i == 0) { rowptr[0] = 0; cursor[0] = 0; }
    if (i < N) {
        int v = rowptr[i + 1] + boff[i >> 8];
        rowptr[i + 1] = v;
        if (i + 1 < N) cursor[i + 1] = v;
    }
}

__global__ __launch_bounds__(256) void fill_kernel(const int* __restrict__ esrc,
                                                   const int* __restrict__ edst, int E, int N,
                                                   int* __restrict__ cursor, int* __restrict__ col) {
    int part = blockIdx.x & (NPART - 1);
    int bIdx = blockIdx.x / NPART;
    int nblk = gridDim.x / NPART;
    int partN = (N + NPART - 1) / NPART;
    int nlo = part * partN;
    int nhi = min(N, nlo + partN);
    int E4 = E >> 2;
    const int4* d4 = (const int4*)edst;
    const int4* s4 = (const int4*)esrc;
    for (int i = bIdx * 256 + threadIdx.x; i < E4; i += nblk * 256) {
        int4 d = d4[i];
        bool mx = (d.x >= nlo) & (d.x < nhi);
        bool my = (d.y >= nlo) & (d.y < nhi);
        bool mz = (d.z >= nlo) & (d.z < nhi);
        bool mw = (d.w >= nlo) & (d.w < nhi);
        if (mx | my | mz | mw) {
            int4 s = s4[i];
            if (mx) col[atomicAdd(&cursor[d.x], 1)] = s.x;
            if (my) col[atomicAdd(&cursor[d.y], 1)] = s.y;
            if (mz) col[atomicAdd(&cursor[d.z], 1)] = s.z;
            if (mw) col[atomicAdd(&cursor[d.w], 1)] = s.w;
        }
    }
    if (blockIdx.x == 0) {
        for (int e = (E4 << 2) + threadIdx.x; e < E; e += 256) {
            int d = edst[e];
            col[atomicAdd(&cursor[d], 1)] = esrc[e];
        }
    }
}

// ---------------------------------------------------------------------------
// Per-layer kernels
// ---------------------------------------------------------------------------
__device__ __forceinline__ ushort f2bf(float x) {
    uint u = __float_as_uint(x);
    u += 0x7fffu + ((u >> 16) & 1u); // RNE
    return (ushort)(u >> 16);
}
__device__ __forceinline__ float bflo(uint u) { return __uint_as_float(u << 16); }
__device__ __forceinline__ float bfhi(uint u) { return __uint_as_float(u & 0xffff0000u); }

// Register-blocked GEMM: block = 128 rows x 64 cols, thread = 8x4 outputs.
// Output layout = half-split bf16: hW[half][(N+1)][32], half-row = 64 B = 1 line.
// Input B (pre-norm h) is also half-split [2][N][32]. BN scale/shift computed
// in-block from the previous layer's raw stats.
template <bool BN>
__global__ __launch_bounds__(256) void gemm_kernel(const float* __restrict__ inF,
                                                   const ushort* __restrict__ inB,
                                                   const float* __restrict__ W,
                                                   const float* __restrict__ stats, // prev layer sum/sumsq
                                                   const float* __restrict__ gamma,
                                                   const float* __restrict__ beta,
                                                   const float* __restrict__ dinv,
                                                   ushort* __restrict__ outb, int N) {
    __shared__ float in_t[D][128]; // 32 KB, [k][row]
    __shared__ float Wl[D][D];     // 16 KB, [k][col]
    __shared__ float bnl[128];
    int t = threadIdx.x;
    if (BN) {
        if (t < 64) {
            float invN = 1.f / (float)N;
            float mean = stats[t] * invN;
            float var  = stats[64 + t] * invN - mean * mean;
            float sc   = gamma[t] * rsqrtf(var + BN_EPS);
            bnl[t]      = sc;
            bnl[64 + t] = beta[t] - mean * sc;
        }
        __syncthreads();
    }
    for (int i = t; i < D * D / 4; i += 256)
        ((float4*)&Wl[0][0])[i] = ((const float4*)W)[i];

    int r = t >> 1;               // 0..127
    int hh = t & 1;               // feature half
    int grow = blockIdx.x * 128 + r;
    if (BN) {
        if (grow < N) {
            const uint* src = (const uint*)(inB + ((size_t)hh * N + grow) * 32);
#pragma unroll
            for (int j = 0; j < 16; ++j) {
                uint u = src[j];
                int f = 32 * hh + 2 * j;
                in_t[f][r]     = fmaxf(fmaf(bflo(u), bnl[f],     bnl[64 + f]),     0.f);
                in_t[f + 1][r] = fmaxf(fmaf(bfhi(u), bnl[f + 1], bnl[64 + f + 1]), 0.f);
            }
        } else {
#pragma unroll
            for (int j = 0; j < 32; ++j) in_t[32 * hh + j][r] = 0.f;
        }
    } else {
        int fbase = hh * 32;
        if (grow < N) {
            const float4* src = (const float4*)(inF + (size_t)grow * D + fbase);
#pragma unroll
            for (int j = 0; j < 8; ++j) {
                float4 v = src[j];
                int f = fbase + 4 * j;
                in_t[f][r] = v.x; in_t[f + 1][r] = v.y; in_t[f + 2][r] = v.z; in_t[f + 3][r] = v.w;
            }
        } else {
#pragma unroll
            for (int j = 0; j < 32; ++j) in_t[fbase + j][r] = 0.f;
        }
    }
    __syncthreads();

    int rg = t & 15;  // rows 8*rg .. 8*rg+7
    int cg = t >> 4;  // cols 4*cg .. 4*cg+3
    float acc[8][4];
#pragma unroll
    for (int i = 0; i < 8; ++i)
#pragma unroll
        for (int j = 0; j < 4; ++j) acc[i][j] = 0.f;

#pragma unroll 8
    for (int k = 0; k < D; ++k) {
        float4 a0 = *(const float4*)&in_t[k][8 * rg];
        float4 a1 = *(const float4*)&in_t[k][8 * rg + 4];
        float4 b  = *(const float4*)&Wl[k][4 * cg];
        float ar[8] = {a0.x, a0.y, a0.z, a0.w, a1.x, a1.y, a1.z, a1.w};
        float br[4] = {b.x, b.y, b.z, b.w};
#pragma unroll
        for (int i = 0; i < 8; ++i)
#pragma unroll
            for (int j = 0; j < 4; ++j)
                acc[i][j] = fmaf(ar[i], br[j], acc[i][j]);
    }

    int oh = cg >> 3; // output feature half
    uint2* dst = (uint2*)(outb + (size_t)oh * (N + 1) * 32);
#pragma unroll
    for (int i = 0; i < 8; ++i) {
        int row = blockIdx.x * 128 + 8 * rg + i;
        if (row < N) {
            float dn = dinv[row];
            uint2 pk;
            pk.x = ((uint)f2bf(acc[i][1] * dn) << 16) | (uint)f2bf(acc[i][0] * dn);
            pk.y = ((uint)f2bf(acc[i][3] * dn) << 16) | (uint)f2bf(acc[i][2] * dn);
            dst[(size_t)row * 8 + (cg & 7)] = pk;
        }
    }
}

// Half-split aggregation, CONTIGUOUS node chunks per block.
// Block's feature half = (blockIdx%8)>>2 (XCDs 0-3 own half 0, 4-7 half 1).
// Each block owns ~N/(G/2) consecutive nodes; its col/rowptr reads are a
// contiguous slice -> per-XCD stream traffic 1/4 of array instead of full
// (kills the 40 MB cross-XCD col duplication seen in R8's FETCH).
// Wave = 1 node; 8 groups x 8 lanes; lane owns 4 features (uint2 = 8 B);
// unroll 4 -> 32 lines in flight. OOB slots read the zero dummy row (index N).
__global__ __launch_bounds__(256) void agg_kernel(const ushort* __restrict__ hW,
                                                  const int* __restrict__ rowptr,
                                                  const int* __restrict__ col,
                                                  const float* __restrict__ dinv,
                                                  ushort* __restrict__ outB,
                                                  float* __restrict__ stats, int N) {
    int part = blockIdx.x & 7;
    int h    = part >> 2;                               // feature half
    int bIdxH = (blockIdx.x >> 3) * 4 + (part & 3);     // block idx within half
    int nBlocksH = gridDim.x >> 1;                      // blocks per half
    const uint2* hw2 = (const uint2*)(hW + (size_t)h * (N + 1) * 32);
    uint2* out2 = (uint2*)(outB + (size_t)h * N * 32);
    int t = threadIdx.x;
    int lane = t & 63;
    int wv   = t >> 6;       // 0..3
    int g    = lane >> 3;    // group 0..7 (edge slot)
    int j    = lane & 7;     // feature quad within half: 4j..4j+3
    float s[4] = {0.f, 0.f, 0.f, 0.f}, q[4] = {0.f, 0.f, 0.f, 0.f};
    int chunk = (N + nBlocksH - 1) / nBlocksH;          // ~98 nodes per block
    int nlo = bIdxH * chunk;
    int nhi = min(N, nlo + chunk);
    for (int n = nlo + wv; n < nhi; n += 4) {
        int e0 = rowptr[n], e1 = rowptr[n + 1];
        float a[4] = {0.f, 0.f, 0.f, 0.f};
        if (g == 0) {
            uint2 us = hw2[(size_t)n * 8 + j];
            a[0] = bflo(us.x); a[1] = bfhi(us.x); a[2] = bflo(us.y); a[3] = bfhi(us.y);
        }
        int m = e1 - 1;
        for (int eb = e0; eb < e1; eb += 32) {
            int cc[4];
            uint2 uu[4];
#pragma unroll
            for (int u = 0; u < 4; ++u) {
                int e = eb + 8 * u + g;
                bool ok = e < e1;
                int c = col[ok ? e : m];
                cc[u] = ok ? c : N; // dummy zero row when past end
            }
#pragma unroll
            for (int u = 0; u < 4; ++u) uu[u] = hw2[(size_t)cc[u] * 8 + j];
#pragma unroll
            for (int u = 0; u < 4; ++u) {
                a[0] += bflo(uu[u].x); a[1] += bfhi(uu[u].x);
                a[2] += bflo(uu[u].y); a[3] += bfhi(uu[u].y);
            }
        }
#pragma unroll
        for (int k = 0; k < 4; ++k) {
            a[k] += __shfl(a[k], lane ^ 8);
            a[k] += __shfl(a[k], lane ^ 16);
            a[k] += __shfl(a[k], lane ^ 32);
        }
        if (g == 0) {
            float dn = dinv[n];
#pragma unroll
            for (int k = 0; k < 4; ++k) { a[k] *= dn; s[k] += a[k]; q[k] += a[k] * a[k]; }
            uint2 pk;
            pk.x = ((uint)f2bf(a[1]) << 16) | (uint)f2bf(a[0]);
            pk.y = ((uint)f2bf(a[3]) << 16) | (uint)f2bf(a[2]);
            out2[(size_t)n * 8 + j] = pk;
        }
    }
    // block-level BN stats for this half's 32 features -> atomics into stats[128]
    __shared__ float red[4][64];
    if (g == 0) {
#pragma unroll
        for (int k = 0; k < 4; ++k) {
            red[wv][4 * j + k]      = s[k];
            red[wv][32 + 4 * j + k] = q[k];
        }
    }
    __syncthreads();
    if (t < 64) {
        float v = red[0][t] + red[1][t] + red[2][t] + red[3][t];
        int f = t & 31;
        int base = (t < 32) ? 0 : 64; // sum block vs sumsq block
        atomicAdd(&stats[base + 32 * h + f], v);
    }
}

// final: read half-split bf16 pre-norm h, apply BN (computed in-block) + ReLU, write fp32
__global__ __launch_bounds__(256) void norm_relu_kernel(const uint* __restrict__ B32,
                                                        const float* __restrict__ stats,
                                                        const float* __restrict__ gamma,
                                                        const float* __restrict__ beta,
                                                        int N, float2* __restrict__ out) {
    __shared__ float bnl[128];
    int t = threadIdx.x;
    if (t < 64) {
        float invN = 1.f / (float)N;
        float mean = stats[t] * invN;
        float var  = stats[64 + t] * invN - mean * mean;
        float sc   = gamma[t] * rsqrtf(var + BN_EPS);
        bnl[t]      = sc;
        bnl[64 + t] = beta[t] - mean * sc;
    }
    __syncthreads();
    int i = blockIdx.x * 256 + t; // over [2][N][16] uints
    int total = N * 32;
    if (i < total) {
        int h = (i >= N * 16) ? 1 : 0;
        int rem = i - h * N * 16;
        int n = rem >> 4;
        int ju = rem & 15;
        int f2 = 32 * h + 2 * ju;
        uint u = B32[i];
        float a = fmaxf(fmaf(bflo(u), bnl[f2],     bnl[64 + f2]),     0.f);
        float b = fmaxf(fmaf(bfhi(u), bnl[f2 + 1], bnl[64 + f2 + 1]), 0.f);
        out[(size_t)n * 32 + 16 * h + ju] = make_float2(a, b);
    }
}

// ---------------------------------------------------------------------------
extern "C" void kernel_launch(void* const* d_in, const int* in_sizes, int n_in,
                              void* d_out, int out_size, void* d_ws, size_t ws_size,
                              hipStream_t stream) {
    const float* x      = (const float*)d_in[0];
    const int*   ei     = (const int*)d_in[1];
    const float* Ws     = (const float*)d_in[2];
    // d_in[3] = bs: cancels exactly under training-mode BatchNorm
    const float* gammas = (const float*)d_in[4];
    const float* betas  = (const float*)d_in[5];

    const int N = in_sizes[0] / D;           // 100000
    const int E = in_sizes[1] / 2;           // 1250000
    const int DEPTH = in_sizes[2] / (D * D); // 4

    const int* esrc = ei;
    const int* edst = ei + E;

    char* w = (char*)d_ws;
    size_t off = 0;
    auto alloc = [&](size_t bytes) {
        void* p = w + off;
        off = (off + bytes + 255) & ~(size_t)255;
        return p;
    };
    ushort* hW     = (ushort*)alloc((size_t)2 * (N + 1) * 32 * sizeof(ushort)); // half-split bf16 (+dummy rows)
    ushort* B      = (ushort*)alloc((size_t)2 * N * 32 * sizeof(ushort));       // half-split bf16 pre-norm h
    int*    counts = (int*)alloc((size_t)N * sizeof(int));                      // | contiguous with
    float*  stats  = (float*)alloc(4 * 128 * sizeof(float));                    // | per-layer stats
    int*    rowptr = (int*)alloc((size_t)(N + 1) * sizeof(int));
    int*    cursor = (int*)alloc((size_t)(N + 1) * sizeof(int));
    float*  dinv   = (float*)alloc((size_t)N * sizeof(float));
    int*    col    = (int*)alloc((size_t)E * sizeof(int));
    int*    bsums  = (int*)alloc(512 * sizeof(int));
    int*    boff   = (int*)alloc(512 * sizeof(int));

    const int nbScan = (N + 255) / 256; // 391

    // single memset covers counts + (alignment pad) + stats
    (void)hipMemsetAsync(counts, 0, (size_t)((char*)(stats + 4 * 128) - (char*)counts), stream);

    // ---- degree + CSR ----
    hist_kernel<<<1024, 256, 0, stream>>>(edst, E, N, counts, (uint*)hW);
    scan1_kernel<<<nbScan, 256, 0, stream>>>(counts, N, rowptr, bsums, dinv);
    scan2_kernel<<<1, 512, 0, stream>>>(bsums, nbScan, boff);
    scan3_kernel<<<nbScan, 256, 0, stream>>>(rowptr, boff, N, cursor);
    fill_kernel<<<1024, 256, 0, stream>>>(esrc, edst, E, N, cursor, col);

    // ---- layers ----
    const int gemmBlocks = (N + 127) / 128; // 782
    const int aggBlocks  = 2048;
    for (int l = 0; l < DEPTH; ++l) {
        const float* W = Ws + (size_t)l * D * D;
        if (l == 0)
            gemm_kernel<false><<<gemmBlocks, 256, 0, stream>>>(x, B, W,
                stats, gammas, betas, dinv, hW, N);
        else
            gemm_kernel<true><<<gemmBlocks, 256, 0, stream>>>(x, B, W,
                stats + (size_t)(l - 1) * 128, gammas + (l - 1) * D, betas + (l - 1) * D,
                dinv, hW, N);
        agg_kernel<<<aggBlocks, 256, 0, stream>>>(hW, rowptr, col, dinv, B,
                                                  stats + (size_t)l * 128, N);
    }
    // final BN + relu: half-split bf16 B -> fp32 d_out
    norm_relu_kernel<<<(N * 32 + 255) / 256, 256, 0, stream>>>((const uint*)B,
        stats + (size_t)(DEPTH - 1) * 128, gammas + (DEPTH - 1) * D, betas + (DEPTH - 1) * D,
        N, (float2*)d_out);
}